// Round 13
// baseline (3006.314 us; speedup 1.0000x reference)
//
#include <hip/hip_runtime.h>
#include <hip/hip_bf16.h>
#include <stdint.h>

typedef unsigned short u16;
typedef unsigned char  u8;
typedef unsigned int   u32;
typedef unsigned long long u64;
typedef __attribute__((ext_vector_type(8))) _Float16 f16x8;
typedef __attribute__((ext_vector_type(4))) float f32x4;

#define TSTEPS 1024
#define BATCH  512
#define INDIM  32
#define HID    256
#define ODIM   32
#define NCH    66
#define KCH    9

// ---------------- workspace layout (bytes) ----------------
// Wb @ 0 (608256); Bc @ 608256 (4096)
// xp u64[32][2][8][128] @ 612352  (524288)  sc0/L2 exchange (tag-in-data)
// xs u64[32][2][8][128] @ 1136640 (524288)  device-scope shadow (ALWAYS written)
#define WS_BC (NCH*KCH*64*8*2)
#define WS_XP (WS_BC + 4096)
#define WS_XS (WS_XP + 32*2*8*128*8)

#define MFMA(a,b,c) __builtin_amdgcn_mfma_f32_16x16x32_f16((a),(b),(c),0,0,0)
#define AGL(p)   __hip_atomic_load((p),      __ATOMIC_RELAXED, __HIP_MEMORY_SCOPE_AGENT)
#define AGS(p,v) __hip_atomic_store((p),(v), __ATOMIC_RELAXED, __HIP_MEMORY_SCOPE_AGENT)

__device__ __forceinline__ u16 f2h(float v){ _Float16 h=(_Float16)v; return *(u16*)&h; }
__device__ __forceinline__ float sigf(float x){ return 1.0f/(1.0f+__expf(-x)); }
__device__ __forceinline__ float tanhf_(float x){
    float ax=fabsf(x); float e=__expf(-2.f*ax); float t=(1.f-e)/(1.f+e); return copysignf(t,x);
}
__device__ __forceinline__ f16x8 cvt8(float4 a, float4 b){
    f16x8 r;
    r[0]=(_Float16)a.x; r[1]=(_Float16)a.y; r[2]=(_Float16)a.z; r[3]=(_Float16)a.w;
    r[4]=(_Float16)b.x; r[5]=(_Float16)b.y; r[6]=(_Float16)b.z; r[7]=(_Float16)b.w;
    return r;
}

// 8x dwordx4 sc0 loads (bypass L1, L2-served), ONE vmcnt(0)
__device__ __forceinline__ void ld8_sc0(const u8* p0, const u8* p1,
    uint4& a, uint4& b, uint4& c, uint4& d, uint4& e, uint4& f, uint4& g, uint4& h){
    asm volatile(
        "global_load_dwordx4 %0, %8, off sc0\n\t"
        "global_load_dwordx4 %1, %8, off offset:1024 sc0\n\t"
        "global_load_dwordx4 %2, %8, off offset:2048 sc0\n\t"
        "global_load_dwordx4 %3, %8, off offset:3072 sc0\n\t"
        "global_load_dwordx4 %4, %9, off sc0\n\t"
        "global_load_dwordx4 %5, %9, off offset:1024 sc0\n\t"
        "global_load_dwordx4 %6, %9, off offset:2048 sc0\n\t"
        "global_load_dwordx4 %7, %9, off offset:3072 sc0\n\t"
        "s_waitcnt vmcnt(0)"
        : "=&v"(a), "=&v"(b), "=&v"(c), "=&v"(d), "=&v"(e), "=&v"(f), "=&v"(g), "=&v"(h)
        : "v"(p0), "v"(p1) : "memory");
    __builtin_amdgcn_sched_barrier(0);
}
__device__ __forceinline__ void st_u64_sc0(u64* p, u64 v){
    asm volatile("global_store_dwordx2 %0, %1, off sc0" :: "v"(p), "v"(v) : "memory");
}

// Pack weights into MFMA B-fragment order (fp16) — unchanged (proven).
__global__ __launch_bounds__(256) void prepack_kernel(
    const float* __restrict__ W_ih, const float* __restrict__ W_hh,
    const float* __restrict__ b_ih, const float* __restrict__ b_hh,
    const float* __restrict__ W_out,
    u16* __restrict__ Wb, float* __restrict__ Bc)
{
    int tid = blockIdx.x*blockDim.x + threadIdx.x;
    int stride = gridDim.x*blockDim.x;
    const int TOT = NCH*KCH*64*8;
    for (int idx = tid; idx < TOT; idx += stride) {
        int j    = idx & 7;
        int lane = (idx >> 3) & 63;
        int ck   = idx >> 9;
        int kc   = ck % KCH;
        int c    = ck / KCH;
        int kl   = ((lane >> 4) << 3) + j;
        float v;
        if (c < 64) {
            int g = c >> 4;
            int m = (c & 15) * 16 + (lane & 15);
            if (kc < 8) v = W_hh[(g*HID + m)*HID + (kc*32 + kl)];
            else        v = W_ih[(g*HID + m)*INDIM + kl];
        } else {
            int o = ((c - 64) << 4) + (lane & 15);
            v = (kc < 8) ? W_out[o*HID + kc*32 + kl] : 0.f;
        }
        Wb[idx] = f2h(v);
    }
    for (int n = tid; n < 1024; n += stride) {
        int c = n >> 4, qq = n & 15;
        int g = c >> 4;
        int m = (c & 15) * 16 + qq;
        Bc[n] = b_ih[g*HID + m] + b_hh[g*HID + m];
    }
}

// Sentinel tag=1 in both buffers every launch (replay-safe).
__global__ __launch_bounds__(256) void init_xbuf_kernel(u64* __restrict__ xp, u64* __restrict__ xs) {
    int i = blockIdx.x*256 + threadIdx.x;
    AGS(xp + i, 1ull);
    AGS(xs + i, 1ull);
}

// 512 blocks x 64 threads; tile = bid&31, ug = bid>>5 (round-robin => all 16
// waves of a tile co-XCD => sc0 polls L2-served). Wave owns units ug*16..+15.
// Publish: tagged u64 via sc0 AND device-scope shadow EVERY step (the shadow
// must always be fresh: a demoted reader polls it, and the init sentinel's
// tag=1 would falsely match gen-1 polls — the R12 bug). Demote is sticky,
// wave-uniform, and safe at any trigger point.
// Projection duty rotates across the 8 waves of each W_out chunk.
__global__ __launch_bounds__(64, 1) void lstm_kernel(
    const float* __restrict__ xin,   // [T][B][32]
    const float* __restrict__ phys,  // [T][B][32]
    const u16*  __restrict__ Wb_,
    const float* __restrict__ Bc,
    const float* __restrict__ b_out,
    u64* __restrict__ xp,            // L2 exchange
    u64* __restrict__ xs,            // L3 shadow
    float* __restrict__ out)         // [2][B][T][32]
{
    const int lane = threadIdx.x;
    const int bid  = blockIdx.x;
    const int tile = bid & 31;
    const int ug   = bid >> 5;
    const int b0   = tile << 4;
    const int q    = lane & 15;
    const int rg   = lane >> 4;
    const int mrb  = rg << 2;
    const int k8   = ug & 7;         // proj-duty phase

    __shared__ u16 scr[256];

    const f16x8* Wb8 = (const f16x8*)Wb_;

    // ---- register-resident weights ----
    f16x8 wg0[KCH], wg1[KCH], wg2[KCH], wg3[KCH];
#pragma unroll
    for (int kc = 0; kc < KCH; ++kc) {
        wg0[kc] = Wb8[((0*16+ug)*KCH + kc)*64 + lane];
        wg1[kc] = Wb8[((1*16+ug)*KCH + kc)*64 + lane];
        wg2[kc] = Wb8[((2*16+ug)*KCH + kc)*64 + lane];
        wg3[kc] = Wb8[((3*16+ug)*KCH + kc)*64 + lane];
    }
    f16x8 wp[8];
#pragma unroll
    for (int kc = 0; kc < 8; ++kc)
        wp[kc] = Wb8[((64 + (ug>>3))*KCH + kc)*64 + lane];

    const float bi0 = Bc[((0*16+ug)<<4)+q];
    const float bi1 = Bc[((1*16+ug)<<4)+q];
    const float bi2 = Bc[((2*16+ug)<<4)+q];
    const float bi3 = Bc[((3*16+ug)<<4)+q];

    const int   o_  = ((ug >> 3) << 4) + q;
    const float bip = b_out[o_];

    // phys for this wave's NEXT duty step (duty t handles outputs t-1)
    float ph0, ph1, ph2, ph3;
    {
        const float* pb = phys + (size_t)k8*BATCH*ODIM + (size_t)(b0+mrb)*ODIM + o_;
        ph0 = pb[0*ODIM]; ph1 = pb[1*ODIM]; ph2 = pb[2*ODIM]; ph3 = pb[3*ODIM];
    }

    // x: axc = fragment for step t (converted); xn = raw floats for step t+1
    const float* xbase = xin + (size_t)(b0 + q)*INDIM + (rg << 3);
    f16x8 axc;
    float4 xn0, xn1;
    {
        float4 c0 = *(const float4*)(xbase);
        float4 c1 = *(const float4*)(xbase + 4);
        axc = cvt8(c0, c1);
        xn0 = *(const float4*)(xbase + (size_t)BATCH*INDIM);
        xn1 = *(const float4*)(xbase + (size_t)BATCH*INDIM + 4);
    }

    // publish constants
    const int m_ = (lane>>1) & 15, s_ = lane>>5, c_ = lane & 1;
    const int gw = ((m_ + 16*(((ug&1)<<1) + s_)) << 1) + c_;
    const int kcSelf = ug >> 1;
    u64* xpT = xp + (size_t)tile*2048;
    u64* xsT = xs + (size_t)tile*2048;

    float* outFull = out;
    float* outRnn  = out + (size_t)BATCH*TSTEPS*ODIM;

    float cs0=0.f, cs1=0.f, cs2=0.f, cs3=0.f;
    f16x8 h0,h1,h2,h3,h4,h5,h6,h7;
    bool fastm = true;

    for (int t = 0; t < TSTEPS; ++t) {
        // ---- phase 1: x-part gates (no h dependency) ----
        f32x4 a0={bi0,bi0,bi0,bi0}, a1={bi1,bi1,bi1,bi1};
        f32x4 a2={bi2,bi2,bi2,bi2}, a3={bi3,bi3,bi3,bi3};
        a0=MFMA(axc,wg0[8],a0); a1=MFMA(axc,wg1[8],a1);
        a2=MFMA(axc,wg2[8],a2); a3=MFMA(axc,wg3[8],a3);

        // ---- phase 2: poll h_{t-1} (tag-in-data; sc0 fast, shadow fallback) ----
        if (t > 0) {
            const u8*  pb0 = (const u8*)xpT + (size_t)(t&1)*8192 + lane*16;
            const u8*  pb1 = pb0 + 4096;
            const u64* sb  = xsT + (size_t)(t&1)*1024 + lane*2;
            const u32  gx  = (u32)(((t-1) >> 1) & 1);
            union U { uint4 u; f16x8 h; u64 qq[2]; } A,B,C,D,E,F,G,H;
            int iter = 0;
            for (;;) {
                if (fastm) {
                    ld8_sc0(pb0, pb1, A.u,B.u,C.u,D.u,E.u,F.u,G.u,H.u);
                } else {
                    A.qq[0]=AGL(sb+0*128); A.qq[1]=AGL(sb+0*128+1);
                    B.qq[0]=AGL(sb+1*128); B.qq[1]=AGL(sb+1*128+1);
                    C.qq[0]=AGL(sb+2*128); C.qq[1]=AGL(sb+2*128+1);
                    D.qq[0]=AGL(sb+3*128); D.qq[1]=AGL(sb+3*128+1);
                    E.qq[0]=AGL(sb+4*128); E.qq[1]=AGL(sb+4*128+1);
                    F.qq[0]=AGL(sb+5*128); F.qq[1]=AGL(sb+5*128+1);
                    G.qq[0]=AGL(sb+6*128); G.qq[1]=AGL(sb+6*128+1);
                    H.qq[0]=AGL(sb+7*128); H.qq[1]=AGL(sb+7*128+1);
                }
                u32 bad = ((A.u.x^gx)|(A.u.z^gx)|(B.u.x^gx)|(B.u.z^gx)
                          |(C.u.x^gx)|(C.u.z^gx)|(D.u.x^gx)|(D.u.z^gx)
                          |(E.u.x^gx)|(E.u.z^gx)|(F.u.x^gx)|(F.u.z^gx)
                          |(G.u.x^gx)|(G.u.z^gx)|(H.u.x^gx)|(H.u.z^gx)) & 1u;
                if (!__any((int)bad)) { h0=A.h;h1=B.h;h2=C.h;h3=D.h;h4=E.h;h5=F.h;h6=G.h;h7=H.h; break; }
                if (fastm && ++iter >= 4096) fastm = false;   // sticky demote; shadow is always fresh
            }
        }

        // ---- phase 3: x shift — convert x[t+1], issue loads for x[t+2] ----
        {
            axc = cvt8(xn0, xn1);   // xn loaded ~1 step ago: drained, cheap wait
            int tt = (t+2 < TSTEPS) ? (t+2) : (TSTEPS-1);
            const float* p = xbase + (size_t)tt*BATCH*INDIM;
            xn0 = *(const float4*)p;
            xn1 = *(const float4*)(p + 4);
        }

        // ---- phase 4: h-part gates ----
        if (t > 0) {
            a0=MFMA(h0,wg0[0],a0); a1=MFMA(h0,wg1[0],a1); a2=MFMA(h0,wg2[0],a2); a3=MFMA(h0,wg3[0],a3);
            a0=MFMA(h1,wg0[1],a0); a1=MFMA(h1,wg1[1],a1); a2=MFMA(h1,wg2[1],a2); a3=MFMA(h1,wg3[1],a3);
            a0=MFMA(h2,wg0[2],a0); a1=MFMA(h2,wg1[2],a1); a2=MFMA(h2,wg2[2],a2); a3=MFMA(h2,wg3[2],a3);
            a0=MFMA(h3,wg0[3],a0); a1=MFMA(h3,wg1[3],a1); a2=MFMA(h3,wg2[3],a2); a3=MFMA(h3,wg3[3],a3);
            a0=MFMA(h4,wg0[4],a0); a1=MFMA(h4,wg1[4],a1); a2=MFMA(h4,wg2[4],a2); a3=MFMA(h4,wg3[4],a3);
            a0=MFMA(h5,wg0[5],a0); a1=MFMA(h5,wg1[5],a1); a2=MFMA(h5,wg2[5],a2); a3=MFMA(h5,wg3[5],a3);
            a0=MFMA(h6,wg0[6],a0); a1=MFMA(h6,wg1[6],a1); a2=MFMA(h6,wg2[6],a2); a3=MFMA(h6,wg3[6],a3);
            a0=MFMA(h7,wg0[7],a0); a1=MFMA(h7,wg1[7],a1); a2=MFMA(h7,wg2[7],a2); a3=MFMA(h7,wg3[7],a3);
        }

        // ---- phase 5: cell update -> transpose -> tagged publish (L2 + L3) ----
        {
            float gi,gf,gg,go,hv;
            gi=sigf(a0[0]); gf=sigf(a1[0]); gg=tanhf_(a2[0]); go=sigf(a3[0]);
            cs0 = gf*cs0 + gi*gg; hv = go*tanhf_(cs0);
            scr[(mrb+0 + 16*(q>>3))*8 + (q&7)] = f2h(hv);
            gi=sigf(a0[1]); gf=sigf(a1[1]); gg=tanhf_(a2[1]); go=sigf(a3[1]);
            cs1 = gf*cs1 + gi*gg; hv = go*tanhf_(cs1);
            scr[(mrb+1 + 16*(q>>3))*8 + (q&7)] = f2h(hv);
            gi=sigf(a0[2]); gf=sigf(a1[2]); gg=tanhf_(a2[2]); go=sigf(a3[2]);
            cs2 = gf*cs2 + gi*gg; hv = go*tanhf_(cs2);
            scr[(mrb+2 + 16*(q>>3))*8 + (q&7)] = f2h(hv);
            gi=sigf(a0[3]); gf=sigf(a1[3]); gg=tanhf_(a2[3]); go=sigf(a3[3]);
            cs3 = gf*cs3 + gi*gg; hv = go*tanhf_(cs3);
            scr[(mrb+3 + 16*(q>>3))*8 + (q&7)] = f2h(hv);

            u16 w0b=scr[lane*4+0], w1b=scr[lane*4+1], w2b=scr[lane*4+2], w3b=scr[lane*4+3];
            u64 pub = (u64)w0b | ((u64)w1b<<16) | ((u64)w2b<<32) | ((u64)w3b<<48);
            pub = (pub & ~1ull) | (u64)((t>>1)&1);
            const size_t off = (size_t)((t+1)&1)*1024 + kcSelf*128 + gw;
            st_u64_sc0(xpT + off, pub);   // L2 (fast consumers)
            AGS(xsT + off, pub);          // L3 shadow (always fresh for fallback)
        }

        // ---- phase 6: rotating projection duty (outputs t-1) ----
        if (t > 0 && k8 == ((t-1) & 7)) {
            f32x4 pa = {bip,bip,bip,bip};
            pa=MFMA(h0,wp[0],pa); pa=MFMA(h1,wp[1],pa);
            pa=MFMA(h2,wp[2],pa); pa=MFMA(h3,wp[3],pa);
            pa=MFMA(h4,wp[4],pa); pa=MFMA(h5,wp[5],pa);
            pa=MFMA(h6,wp[6],pa); pa=MFMA(h7,wp[7],pa);
            const size_t ob = (size_t)(b0+mrb)*TSTEPS*ODIM + (size_t)(t-1)*ODIM + o_;
            const size_t rs = (size_t)TSTEPS*ODIM;
            outFull[ob+0*rs] = ph0 + pa[0];  outRnn[ob+0*rs] = pa[0];
            outFull[ob+1*rs] = ph1 + pa[1];  outRnn[ob+1*rs] = pa[1];
            outFull[ob+2*rs] = ph2 + pa[2];  outRnn[ob+2*rs] = pa[2];
            outFull[ob+3*rs] = ph3 + pa[3];  outRnn[ob+3*rs] = pa[3];
            // prefetch phys for next duty (outputs t+7), guarded
            int tn = (t + 7 <= TSTEPS-1) ? (t + 7) : (TSTEPS-1);
            const float* pb = phys + (size_t)tn*BATCH*ODIM + (size_t)(b0+mrb)*ODIM + o_;
            ph0 = pb[0*ODIM]; ph1 = pb[1*ODIM]; ph2 = pb[2*ODIM]; ph3 = pb[3*ODIM];
        }
    }

    // ---- epilogue: outputs 1023 by duty waves k8==7 (h_1023: parity 0, tag 1) ----
    if (k8 == 7) {
        const u8*  pb0 = (const u8*)xpT + lane*16;
        const u8*  pb1 = pb0 + 4096;
        const u64* sb  = xsT + lane*2;
        union U { uint4 u; f16x8 h; u64 qq[2]; } A,B,C,D,E,F,G,H;
        int iter = 0;
        for (;;) {
            if (fastm) {
                ld8_sc0(pb0, pb1, A.u,B.u,C.u,D.u,E.u,F.u,G.u,H.u);
            } else {
                A.qq[0]=AGL(sb+0*128); A.qq[1]=AGL(sb+0*128+1);
                B.qq[0]=AGL(sb+1*128); B.qq[1]=AGL(sb+1*128+1);
                C.qq[0]=AGL(sb+2*128); C.qq[1]=AGL(sb+2*128+1);
                D.qq[0]=AGL(sb+3*128); D.qq[1]=AGL(sb+3*128+1);
                E.qq[0]=AGL(sb+4*128); E.qq[1]=AGL(sb+4*128+1);
                F.qq[0]=AGL(sb+5*128); F.qq[1]=AGL(sb+5*128+1);
                G.qq[0]=AGL(sb+6*128); G.qq[1]=AGL(sb+6*128+1);
                H.qq[0]=AGL(sb+7*128); H.qq[1]=AGL(sb+7*128+1);
            }
            u32 bad = ((A.u.x^1u)|(A.u.z^1u)|(B.u.x^1u)|(B.u.z^1u)
                      |(C.u.x^1u)|(C.u.z^1u)|(D.u.x^1u)|(D.u.z^1u)
                      |(E.u.x^1u)|(E.u.z^1u)|(F.u.x^1u)|(F.u.z^1u)
                      |(G.u.x^1u)|(G.u.z^1u)|(H.u.x^1u)|(H.u.z^1u)) & 1u;
            if (!__any((int)bad)) { h0=A.h;h1=B.h;h2=C.h;h3=D.h;h4=E.h;h5=F.h;h6=G.h;h7=H.h; break; }
            if (fastm && ++iter >= 4096) fastm = false;
        }
        f32x4 pa = {bip,bip,bip,bip};
        pa=MFMA(h0,wp[0],pa); pa=MFMA(h1,wp[1],pa);
        pa=MFMA(h2,wp[2],pa); pa=MFMA(h3,wp[3],pa);
        pa=MFMA(h4,wp[4],pa); pa=MFMA(h5,wp[5],pa);
        pa=MFMA(h6,wp[6],pa); pa=MFMA(h7,wp[7],pa);
        const size_t ob = (size_t)(b0+mrb)*TSTEPS*ODIM + (size_t)1023*ODIM + o_;
        const size_t rs = (size_t)TSTEPS*ODIM;
        outFull[ob+0*rs] = ph0 + pa[0];  outRnn[ob+0*rs] = pa[0];
        outFull[ob+1*rs] = ph1 + pa[1];  outRnn[ob+1*rs] = pa[1];
        outFull[ob+2*rs] = ph2 + pa[2];  outRnn[ob+2*rs] = pa[2];
        outFull[ob+3*rs] = ph3 + pa[3];  outRnn[ob+3*rs] = pa[3];
    }
}

extern "C" void kernel_launch(void* const* d_in, const int* in_sizes, int n_in,
                              void* d_out, int out_size, void* d_ws, size_t ws_size,
                              hipStream_t stream) {
    const float* xin   = (const float*)d_in[0];
    const float* phys  = (const float*)d_in[1];
    const float* W_ih  = (const float*)d_in[2];
    const float* W_hh  = (const float*)d_in[3];
    const float* b_ih  = (const float*)d_in[4];
    const float* b_hh  = (const float*)d_in[5];
    const float* W_out = (const float*)d_in[6];
    const float* b_out = (const float*)d_in[7];

    char*  ws = (char*)d_ws;
    u16*   Wb = (u16*)ws;
    float* Bc = (float*)(ws + WS_BC);
    u64*   xp = (u64*)(ws + WS_XP);
    u64*   xs = (u64*)(ws + WS_XS);

    prepack_kernel<<<256, 256, 0, stream>>>(W_ih, W_hh, b_ih, b_hh, W_out, Wb, Bc);
    init_xbuf_kernel<<<256, 256, 0, stream>>>(xp, xs);
    lstm_kernel<<<512, 64, 0, stream>>>(xin, phys, Wb, Bc, b_out, xp, xs, (float*)d_out);
}